// Round 15
// baseline (267.430 us; speedup 1.0000x reference)
//
#include <hip/hip_runtime.h>

// Modulated deformable conv, fp32 in/out. B=4, CIN=COUT=256, H=W=64, KS=3, PAD=1.
// R15: ONE plain kernel (grid 512 x 512thr = R12's proven shape) with a
// device-scope atomic spin barrier instead of cooperative launch (R14's coop
// launch was rejected -> zero output). Co-residency: LDS 40.7KB -> 3 blk/CU,
// waves -> 4, VGPR<<128 -> capacity >= 768 > grid 512. Counter in ws, memset
// per call. Phase 0: wfrag swizzle + xpairT transpose; phase 1 staging now
// coalesced direct-x loads; phases 1-3 otherwise = R12 (88us measured).
// ws: [xpairT 16MB][wfrag 1.33MB][cnt 4B]; fp32-gather fallback if ws small.

#define WOFF_FRAG_OFF 589824
#define GRIDN 512u
typedef unsigned short ushort_t;
typedef unsigned int   uint_t;

using short8 = __attribute__((ext_vector_type(8))) short;
using f32x4  = __attribute__((ext_vector_type(4))) float;

struct __attribute__((packed, aligned(4))) pairf { float x, y; };

__device__ inline ushort_t f2bf(float v) {
    unsigned u = __float_as_uint(v);
    unsigned r = u + 0x7fffu + ((u >> 16) & 1u);   // RNE (inputs finite)
    return (ushort_t)(r >> 16);
}
__device__ inline float bflo(uint_t u) { return __uint_as_float(u << 16); }
__device__ inline float bfhi(uint_t u) { return __uint_as_float(u & 0xffff0000u); }

template<bool USE_PAIR>
__global__ __launch_bounds__(512, 4) void k_fused(
    const float* __restrict__ x,
    const float* __restrict__ w_conv,
    const float* __restrict__ w_off,
    const float* __restrict__ b_off,
    ushort_t* __restrict__ wfrag,
    uint_t* __restrict__ xpair,
    uint_t* __restrict__ cnt,
    float* __restrict__ out)
{
    __shared__ short As[2][32 * 264];                // 33,792 B
    __shared__ __align__(16) float4 pwt[9 * 32];
    __shared__ __align__(16) int2   pidx[9 * 32];
    float*  om_s = (float*)&As[0][0];                // 32c x 32px fp32 alias
    uint_t* tl   = (uint_t*)&As[0][0];               // 32x256 transpose tile alias

    const int bid = blockIdx.x;
    const int tid = threadIdx.x;

    // ================= phase 0a: weight swizzle (blocks 0..161) =================
    if (bid < 162) {
        const int i8 = bid * 512 + tid;              // 0..82,943 fragment rows
        if (i8 < 73728) {                            // w_conv (HW-verified R13)
            const int lane = i8 & 63;
            const int nt = (i8 >> 6) & 15;
            const int kt = i8 >> 10;                 // 0..71
            const int n = nt * 16 + (lane & 15);
            const int k0 = kt * 32 + ((lane >> 4) << 3);
            ushort_t v[8];
#pragma unroll
            for (int j = 0; j < 8; ++j) {
                const int kn = k0 + j;               // tap-outer: kn = tap*256+cin
                const int cin = kn & 255, tap = kn >> 8;
                v[j] = f2bf(w_conv[n * 2304 + cin * 9 + tap]);
            }
            uint4 o;
            o.x = (uint_t)v[0] | ((uint_t)v[1] << 16);
            o.y = (uint_t)v[2] | ((uint_t)v[3] << 16);
            o.z = (uint_t)v[4] | ((uint_t)v[5] << 16);
            o.w = (uint_t)v[6] | ((uint_t)v[7] << 16);
            *(uint4*)(wfrag + (size_t)i8 * 8) = o;
        } else {                                     // w_off (+ zero pad n>=27)
            const int s8 = i8 - 73728;               // 0..9215
            const int lane = s8 & 63;
            const int nt = (s8 >> 6) & 1;
            const int kt = s8 >> 7;                  // 0..71
            const int n = nt * 16 + (lane & 15);
            const int k0 = kt * 32 + ((lane >> 4) << 3);
            ushort_t v[8];
#pragma unroll
            for (int j = 0; j < 8; ++j) {
                const int kn = k0 + j;
                const int cin = kn & 255, tap = kn >> 8;
                v[j] = (n < 27) ? f2bf(w_off[n * 2304 + cin * 9 + tap]) : (ushort_t)0;
            }
            uint4 o;
            o.x = (uint_t)v[0] | ((uint_t)v[1] << 16);
            o.y = (uint_t)v[2] | ((uint_t)v[3] << 16);
            o.z = (uint_t)v[4] | ((uint_t)v[5] << 16);
            o.w = (uint_t)v[6] | ((uint_t)v[7] << 16);
            *(uint4*)(wfrag + WOFF_FRAG_OFF + (size_t)s8 * 8) = o;
        }
    }

    // ================= phase 0b: xpairT transpose (all 512 blocks) ==============
    if (USE_PAIR) {
        const int tb    = bid >> 7;                  // batch
        const int idx0  = (bid & 127) << 5;          // 32 idx rows per block
        const int cin   = tid & 255;
        const int ih    = tid >> 8;                  // 0/1 -> 16 idx each
        const int myidx = idx0 + (ih << 4);
        const float* xp = x + (tb << 20) + (cin << 12) + myidx;
        float v[17];
#pragma unroll
        for (int g = 0; g < 4; ++g) {
            const float4 f = *(const float4*)(xp + g * 4);
            v[4 * g] = f.x; v[4 * g + 1] = f.y; v[4 * g + 2] = f.z; v[4 * g + 3] = f.w;
        }
        v[16] = ((myidx & 63) != 48) ? xp[16] : 0.f; // pair-hi never crosses 64-row
#pragma unroll
        for (int i = 0; i < 16; ++i)
            tl[((ih << 4) + i) * 256 + cin] =
                (uint_t)f2bf(v[i]) | ((uint_t)f2bf(v[i + 1]) << 16);
        __syncthreads();
        uint_t* op = xpair + (((tb << 12) + idx0) << 8);
#pragma unroll
        for (int r = 0; r < 4; ++r) {
            const int l = r * 512 + tid;
            const int il = l >> 6, c = (l & 63) << 2;
            *(uint4*)(op + (il << 8) + c) = *(const uint4*)&tl[il * 256 + c];
        }
    }

    // ================= grid-wide spin barrier (device-scope atomics) ============
    __syncthreads();
    if (tid == 0) {
        __threadfence();                             // release wfrag/xpair stores
        atomicAdd(cnt, 1u);                          // device-scope (m20)
        while (__hip_atomic_load(cnt, __ATOMIC_ACQUIRE, __HIP_MEMORY_SCOPE_AGENT) < GRIDN) {}
        __threadfence();                             // acquire others' stores
    }
    __syncthreads();

    // ======================= R12 main body (phases 1-3) =========================
    const int sid = ((bid & 7) << 6) | (bid >> 3);   // XCD-contiguous bands
    const int m0  = sid << 5;
    const int b   = m0 >> 12;
    const int h   = (m0 >> 6) & 63;
    const int wbase = m0 & 63;                        // 0 or 32
    const int lane = tid & 63;
    const int wv   = tid >> 6;                        // 0..7
    const int quad = lane >> 4;
    const int px   = tid & 31;                        // staging pixel
    const int slot = tid >> 5;                        // 0..15: 16 cins each

    const float*  xb = x + (b << 20);
    const uint_t* xq = xpair + (b << 20);
    const ushort_t* woffb = wfrag + WOFF_FRAG_OFF;

    // ---------- phase 1: offset conv via MFMA; staging = coalesced x loads ------
    const int m_w = wv & 1, nt_w = (wv >> 1) & 1;     // waves 0..3 cover 2m x 2nt
    f32x4 om_acc = {0.f, 0.f, 0.f, 0.f};

    auto stage1 = [&](int tap, int bufi) {
        const int ky = (tap * 11) >> 5, kx = tap - ky * 3;
        const int yy = h + ky - 1;
        const int xx = wbase + px + kx - 1;
        const bool v = ((unsigned)yy < 64u) & ((unsigned)xx < 64u);
        const int idx = v ? (yy << 6) + xx : 0;
        const float* p = xb + ((slot << 4) << 12) + idx;   // coalesced over px
        uint_t o[8];
#pragma unroll
        for (int k = 0; k < 8; ++k) {
            float t0 = p[(2 * k) << 12];
            float t1 = p[(2 * k + 1) << 12];
            t0 = v ? t0 : 0.f;  t1 = v ? t1 : 0.f;
            o[k] = (uint_t)f2bf(t0) | ((uint_t)f2bf(t1) << 16);
        }
        uint_t* dst = (uint_t*)&As[bufi][0] + px * 132 + slot * 8;
        *(uint4*)dst       = make_uint4(o[0], o[1], o[2], o[3]);
        *(uint4*)(dst + 4) = make_uint4(o[4], o[5], o[6], o[7]);
    };
    auto mfma1 = [&](int tap) {
        if (wv < 4) {
            const short* cur = &As[tap & 1][0];
#pragma unroll
            for (int k2 = 0; k2 < 8; ++k2) {
                const int ktg = tap * 8 + k2;
                const short8 a = *(const short8*)&cur[((m_w << 4) + (lane & 15)) * 264 + k2 * 32 + quad * 8];
                const short8 bf = *(const short8*)(woffb + ((ktg * 2 + nt_w) * 64 + lane) * 8);
                om_acc = __builtin_amdgcn_mfma_f32_16x16x32_bf16(a, bf, om_acc, 0, 0, 0);
            }
        }
    };

    stage1(0, 0);
    __syncthreads();
    for (int tap = 0; tap < 9; ++tap) {
        if (tap < 8) stage1(tap + 1, (tap + 1) & 1);
        mfma1(tap);
        __syncthreads();
    }
    if (wv < 4) {   // C/D: px = m_w*16 + quad*4 + reg; c = nt_w*16 + (lane&15)
        const int c = (nt_w << 4) + (lane & 15);
        *(f32x4*)&om_s[c * 32 + (m_w << 4) + (quad << 2)] = om_acc;
    }
    __syncthreads();

    // ---------- phase 2: per-(tap,px) pair-gather params ----------
    if (tid < 288) {
        const int p2 = tid & 31, tap = tid >> 5;
        const int ky = (tap * 11) >> 5, kx = tap - ky * 3;
        const float dyv = om_s[(2 * tap) * 32 + p2] + b_off[2 * tap];
        const float dxv = om_s[(2 * tap + 1) * 32 + p2] + b_off[2 * tap + 1];
        const float mo  = om_s[(18 + tap) * 32 + p2] + b_off[18 + tap];
        const float mv  = 1.f / (1.f + expf(-mo));
        const float py  = dyv + (float)(h - 1 + ky);
        const float pxf = dxv + (float)(wbase + p2 - 1 + kx);
        const float y0f = floorf(py), x0f = floorf(pxf);
        const float wy = py - y0f,    wx = pxf - x0f;
        const float vy0 = (y0f >=  0.f && y0f <= 63.f) ? 1.f : 0.f;
        const float vy1 = (y0f >= -1.f && y0f <= 62.f) ? 1.f : 0.f;
        const int ry0 = (int)fminf(fmaxf(y0f, 0.f), 63.f);
        const int ry1 = (int)fminf(fmaxf(y0f + 1.f, 0.f), 63.f);
        const float rw0 = (1.f - wy) * vy0 * mv;
        const float rw1 = wy * vy1 * mv;
        const bool in01 = (x0f >= 0.f && x0f <= 62.f);
        const float wa = in01 ? (1.f - wx) : ((x0f == -1.f) ? wx : 0.f);
        const float wb = in01 ? wx : ((x0f == 63.f) ? (1.f - wx) : 0.f);
        const int bx = (int)fminf(fmaxf(x0f, 0.f), 62.f);
        pwt[tid]  = make_float4(wa, wb, rw0, rw1);
        pidx[tid] = make_int2(ry0 * 64 + bx, ry1 * 64 + bx);
    }
    __syncthreads();

    // ---------- phase 3: sampling + main GEMM (R12 verbatim) ----------
    f32x4 acc[2][2];
#pragma unroll
    for (int m = 0; m < 2; ++m)
#pragma unroll
        for (int nn = 0; nn < 2; ++nn) acc[m][nn] = f32x4{0.f, 0.f, 0.f, 0.f};

    const int nt_base = wv << 1;                      // wave's couts: wv*32..+31

    auto stage3 = [&](int tap, int bufi) {
        const float4 wt = pwt[tap * 32 + px];
        const int2   ii = pidx[tap * 32 + px];
        uint_t o[8];
        if (USE_PAIR) {
            const uint_t* p0 = xq + (ii.x << 8) + (slot << 4);
            const uint_t* p1 = xq + (ii.y << 8) + (slot << 4);
            uint4 r0[4], r1[4];
#pragma unroll
            for (int g = 0; g < 4; ++g) {
                r0[g] = *(const uint4*)(p0 + g * 4);
                r1[g] = *(const uint4*)(p1 + g * 4);
            }
            const uint_t* a0 = (const uint_t*)r0;
            const uint_t* a1 = (const uint_t*)r1;
#pragma unroll
            for (int k = 0; k < 8; ++k) {
                ushort_t s[2];
#pragma unroll
                for (int u = 0; u < 2; ++u) {
                    const int c = 2 * k + u;
                    const float v = (bflo(a0[c]) * wt.x + bfhi(a0[c]) * wt.y) * wt.z
                                  + (bflo(a1[c]) * wt.x + bfhi(a1[c]) * wt.y) * wt.w;
                    s[u] = f2bf(v);
                }
                o[k] = (uint_t)s[0] | ((uint_t)s[1] << 16);
            }
        } else {
#pragma unroll
            for (int k = 0; k < 8; ++k) {
                ushort_t s[2];
#pragma unroll
                for (int u = 0; u < 2; ++u) {
                    const int cin = (slot << 4) + 2 * k + u;
                    const pairf pa = *(const pairf*)(xb + (cin << 12) + ii.x);
                    const pairf pb = *(const pairf*)(xb + (cin << 12) + ii.y);
                    const float v = (pa.x * wt.x + pa.y * wt.y) * wt.z
                                  + (pb.x * wt.x + pb.y * wt.y) * wt.w;
                    s[u] = f2bf(v);
                }
                o[k] = (uint_t)s[0] | ((uint_t)s[1] << 16);
            }
        }
        uint_t* dst = (uint_t*)&As[bufi][0] + px * 132 + slot * 8;
        *(uint4*)dst       = make_uint4(o[0], o[1], o[2], o[3]);
        *(uint4*)(dst + 4) = make_uint4(o[4], o[5], o[6], o[7]);
    };
    auto mfma3 = [&](int tap) {
        const short* cur = &As[tap & 1][0];
#pragma unroll
        for (int k2 = 0; k2 < 8; ++k2) {
            const int ktg = tap * 8 + k2;
            short8 a0 = *(const short8*)&cur[(lane & 15) * 264 + k2 * 32 + quad * 8];
            short8 a1 = *(const short8*)&cur[((lane & 15) + 16) * 264 + k2 * 32 + quad * 8];
#pragma unroll
            for (int nn = 0; nn < 2; ++nn) {
                const short8 bf = *(const short8*)(wfrag + ((ktg * 16 + nt_base + nn) * 64 + lane) * 8);
                acc[0][nn] = __builtin_amdgcn_mfma_f32_16x16x32_bf16(a0, bf, acc[0][nn], 0, 0, 0);
                acc[1][nn] = __builtin_amdgcn_mfma_f32_16x16x32_bf16(a1, bf, acc[1][nn], 0, 0, 0);
            }
        }
    };

    stage3(0, 0);
    __syncthreads();
    for (int tap = 0; tap < 9; ++tap) {
        if (tap < 8) stage3(tap + 1, (tap + 1) & 1);
        mfma3(tap);
        __syncthreads();
    }

    // epilogue: w = wbase + m*16 + quad*4 + reg; cout n = wv*32 + nn*16 + (lane&15)
#pragma unroll
    for (int m = 0; m < 2; ++m) {
        const int w = wbase + (m << 4) + (quad << 2);
#pragma unroll
        for (int nn = 0; nn < 2; ++nn) {
            const int n = (wv << 5) + (nn << 4) + (lane & 15);
            float* op = out + (((size_t)((b << 8) + n)) << 12) + (h << 6) + w;
            *(f32x4*)op = acc[m][nn];
        }
    }
}

extern "C" void kernel_launch(void* const* d_in, const int* in_sizes, int n_in,
                              void* d_out, int out_size, void* d_ws, size_t ws_size,
                              hipStream_t stream) {
    const float* x      = (const float*)d_in[0];
    const float* w_off  = (const float*)d_in[1];
    const float* b_off  = (const float*)d_in[2];
    const float* w_conv = (const float*)d_in[3];
    float* out = (float*)d_out;

    const size_t xp_bytes = 4194304ull * 4;          // 16 MB
    const size_t wf_bytes = 663552ull * 2;           // 1.33 MB
    const bool use_pair = (ws_size >= xp_bytes + wf_bytes + 64);

    uint_t*   xpair = (uint_t*)d_ws;
    ushort_t* wfrag = use_pair ? (ushort_t*)((char*)d_ws + xp_bytes)
                               : (ushort_t*)d_ws;
    uint_t*   cnt   = use_pair ? (uint_t*)((char*)d_ws + xp_bytes + wf_bytes)
                               : (uint_t*)((char*)d_ws + wf_bytes);

    hipMemsetAsync(cnt, 0, 4, stream);               // reset barrier counter

    if (use_pair)
        hipLaunchKernelGGL((k_fused<true>), dim3(512), dim3(512), 0, stream,
                           x, w_conv, w_off, b_off, wfrag, xpair, cnt, out);
    else
        hipLaunchKernelGGL((k_fused<false>), dim3(512), dim3(512), 0, stream,
                           x, w_conv, w_off, b_off, wfrag, xpair, cnt, out);
}

// Round 16
// 177.650 us; speedup vs baseline: 1.5054x; 1.5054x over previous
//
#include <hip/hip_runtime.h>
#include <hip/hip_bf16.h>

// Modulated deformable conv, fp32 in/out. B=4, CIN=COUT=256, H=W=64, KS=3, PAD=1.
// R16: R12 two-kernel structure (k_all 88us measured) minus phase 1: the om
// offset-conv GEMM moves to prep (dense MFMA, writes om_g). 3 dispatches
// (k_pre_w -> k_pre_x -> k_all); R15 proved extra dispatches are ~free and
// fusion/spin-barriers are a loss. Phase-3: 4-weight folded bilinear +
// cvt_pk_bf16 packing. ws: [xpairT 16MB][wfrag 1.33MB][om_g 2MB], laddered
// fallback (R12-verbatim if om_g doesn't fit; fp32-direct if nothing fits).

#define WOFF_FRAG_OFF 589824
typedef unsigned short ushort_t;
typedef unsigned int   uint_t;

using short8 = __attribute__((ext_vector_type(8))) short;
using f32x4  = __attribute__((ext_vector_type(4))) float;

struct __attribute__((packed, aligned(4))) pairf { float x, y; };

__device__ inline ushort_t f2bf(float v) {
    unsigned u = __float_as_uint(v);
    unsigned r = u + 0x7fffu + ((u >> 16) & 1u);   // RNE (inputs finite)
    return (ushort_t)(r >> 16);
}
__device__ inline uint_t packbf2(float a, float b) {
    __hip_bfloat162 h = __float22bfloat162_rn(make_float2(a, b));
    return *(uint_t*)&h;                            // lo = a, hi = b
}
__device__ inline float bflo(uint_t u) { return __uint_as_float(u << 16); }
__device__ inline float bfhi(uint_t u) { return __uint_as_float(u & 0xffff0000u); }

// ---- k_pre_w: wfrag swizzle, 324 blocks (HW-verified R13) ----
__global__ __launch_bounds__(256) void k_pre_w(
    const float* __restrict__ w_conv,
    const float* __restrict__ w_off,
    ushort_t* __restrict__ wfrag)
{
    const int wb = blockIdx.x;
    const int t  = threadIdx.x;
    if (wb < 288) {                                   // w_conv fragment rows
        const int i8 = wb * 256 + t;                  // 0..73727
        const int lane = i8 & 63;
        const int nt = (i8 >> 6) & 15;
        const int kt = i8 >> 10;                      // 0..71
        const int n = nt * 16 + (lane & 15);
        const int k0 = kt * 32 + ((lane >> 4) << 3);
        ushort_t v[8];
#pragma unroll
        for (int j = 0; j < 8; ++j) {
            const int kn = k0 + j;                    // tap-outer: kn = tap*256+cin
            const int cin = kn & 255, tap = kn >> 8;
            v[j] = f2bf(w_conv[n * 2304 + cin * 9 + tap]);
        }
        uint4 o;
        o.x = (uint_t)v[0] | ((uint_t)v[1] << 16);
        o.y = (uint_t)v[2] | ((uint_t)v[3] << 16);
        o.z = (uint_t)v[4] | ((uint_t)v[5] << 16);
        o.w = (uint_t)v[6] | ((uint_t)v[7] << 16);
        *(uint4*)(wfrag + (size_t)i8 * 8) = o;
    } else {                                          // w_off fragment rows (+pad)
        const int i8 = (wb - 288) * 256 + t;          // 0..9215
        const int lane = i8 & 63;
        const int nt = (i8 >> 6) & 1;
        const int kt = i8 >> 7;                       // 0..71
        const int n = nt * 16 + (lane & 15);
        const int k0 = kt * 32 + ((lane >> 4) << 3);
        ushort_t v[8];
#pragma unroll
        for (int j = 0; j < 8; ++j) {
            const int kn = k0 + j;
            const int cin = kn & 255, tap = kn >> 8;
            v[j] = (n < 27) ? f2bf(w_off[n * 2304 + cin * 9 + tap]) : (ushort_t)0;
        }
        uint4 o;
        o.x = (uint_t)v[0] | ((uint_t)v[1] << 16);
        o.y = (uint_t)v[2] | ((uint_t)v[3] << 16);
        o.z = (uint_t)v[4] | ((uint_t)v[5] << 16);
        o.w = (uint_t)v[6] | ((uint_t)v[7] << 16);
        *(uint4*)(wfrag + WOFF_FRAG_OFF + (size_t)i8 * 8) = o;
    }
}

// ---- k_pre_x: blocks [0,XO): om GEMM (needs wfrag from k_pre_w);
//      blocks [XO, XO+XT): xpairT transpose (R13-verified form). ----
__global__ __launch_bounds__(256) void k_pre_x(
    const float* __restrict__ x,
    const ushort_t* __restrict__ wfrag,
    uint_t* __restrict__ xpair,
    float* __restrict__ om_g,
    int XO)
{
    __shared__ short As[2][32 * 264];                 // 33,792 B (tl aliases)
    uint_t* tl = (uint_t*)&As[0][0];

    const int bid = blockIdx.x;
    const int tid = threadIdx.x;

    if (bid < XO) {
        // ---- om GEMM block: 32 px x 32 n, K=2304 (tap-outer), 4 waves ----
        const int sid = ((bid & 7) << 6) | (bid >> 3);
        const int m0  = sid << 5;
        const int b   = m0 >> 12;
        const int h   = (m0 >> 6) & 63;
        const int wbase = m0 & 63;
        const int lane = tid & 63;
        const int wv   = tid >> 6;                    // 0..3
        const int quad = lane >> 4;
        const int px   = tid & 31;
        const int slot = tid >> 5;                    // 0..7: 32 cins each
        const float* xb = x + (b << 20);
        const ushort_t* woffb = wfrag + WOFF_FRAG_OFF;
        const int m_w = wv & 1, nt_w = wv >> 1;

        f32x4 om_acc = {0.f, 0.f, 0.f, 0.f};

        auto stage = [&](int tap, int bufi) {
            const int ky = (tap * 11) >> 5, kx = tap - ky * 3;
            const int yy = h + ky - 1;
            const int xx = wbase + px + kx - 1;
            const bool v = ((unsigned)yy < 64u) & ((unsigned)xx < 64u);
            const int idx = v ? (yy << 6) + xx : 0;
            const float* p = xb + ((slot << 5) << 12) + idx;
            uint_t* dst = (uint_t*)&As[bufi][0] + px * 132 + (slot << 4);
#pragma unroll
            for (int k = 0; k < 16; ++k) {
                float t0 = p[(2 * k) << 12];
                float t1 = p[(2 * k + 1) << 12];
                t0 = v ? t0 : 0.f;  t1 = v ? t1 : 0.f;
                dst[k] = packbf2(t0, t1);
            }
        };
        auto domfma = [&](int tap) {
            const short* cur = &As[tap & 1][0];
#pragma unroll
            for (int k2 = 0; k2 < 8; ++k2) {
                const int ktg = tap * 8 + k2;
                const short8 a = *(const short8*)&cur[((m_w << 4) + (lane & 15)) * 264 + k2 * 32 + quad * 8];
                const short8 bf = *(const short8*)(woffb + ((ktg * 2 + nt_w) * 64 + lane) * 8);
                om_acc = __builtin_amdgcn_mfma_f32_16x16x32_bf16(a, bf, om_acc, 0, 0, 0);
            }
        };

        stage(0, 0);
        __syncthreads();
        for (int tap = 0; tap < 9; ++tap) {
            if (tap < 8) stage(tap + 1, (tap + 1) & 1);
            domfma(tap);
            __syncthreads();
        }
        // C/D: px_loc = m_w*16 + quad*4 + reg; c = nt_w*16 + (lane&15)
        const int c = (nt_w << 4) + (lane & 15);
        *(f32x4*)(om_g + sid * 1024 + c * 32 + (m_w << 4) + (quad << 2)) = om_acc;
        return;
    }

    // ---- transpose block (R13-verified): 16 idx x 256 cin ----
    const int tb2  = bid - XO;
    const int b    = tb2 >> 8;
    const int idx0 = (tb2 & 255) << 4;
    const float* xp = x + (b << 20) + (tid << 12) + idx0;
    float v[17];
#pragma unroll
    for (int g = 0; g < 4; ++g) {
        const float4 f = *(const float4*)(xp + g * 4);
        v[4 * g] = f.x; v[4 * g + 1] = f.y; v[4 * g + 2] = f.z; v[4 * g + 3] = f.w;
    }
    v[16] = ((idx0 & 63) != 48) ? xp[16] : 0.f;       // pair-hi never crosses row
#pragma unroll
    for (int i = 0; i < 16; ++i)
        tl[i * 256 + tid] = packbf2(v[i], v[i + 1]);
    __syncthreads();
    uint_t* op = xpair + (((b << 12) + idx0) << 8);
#pragma unroll
    for (int r = 0; r < 4; ++r) {
        const int l = r * 256 + tid;
        const int il = l >> 6, c = (l & 63) << 2;
        *(uint4*)(op + (il << 8) + c) = *(const uint4*)&tl[il * 256 + c];
    }
}

// ---- k_all: block = 32 px x 256 couts, 512 thr = 8 waves, grid 512 ----
template<bool USE_PAIR, bool OM_PRE>
__global__ __launch_bounds__(512, 4) void k_all(
    const float* __restrict__ x,
    const uint_t* __restrict__ xpair,
    const float* __restrict__ b_off,
    const ushort_t* __restrict__ wfrag,
    const float* __restrict__ om_g,
    float* __restrict__ out)
{
    __shared__ short As[2][32 * 264];                // 33,792 B
    __shared__ __align__(16) float4 pwt[9 * 32];
    __shared__ __align__(16) int2   pidx[9 * 32];
    float* om_s = (float*)&As[0][0];                 // used only when !OM_PRE

    const int bid = blockIdx.x;
    const int sid = ((bid & 7) << 6) | (bid >> 3);   // XCD-contiguous bands
    const int m0  = sid << 5;
    const int b   = m0 >> 12;
    const int h   = (m0 >> 6) & 63;
    const int wbase = m0 & 63;                        // 0 or 32
    const int tid  = threadIdx.x;
    const int lane = tid & 63;
    const int wv   = tid >> 6;                        // 0..7
    const int quad = lane >> 4;
    const int px   = tid & 31;                        // staging pixel
    const int slot = tid >> 5;                        // 0..15: 16 cins each

    const float*  xb = x + (b << 20);
    const uint_t* xq = xpair + (b << 20);
    const ushort_t* woffb = wfrag + WOFF_FRAG_OFF;

    // ---------- phase 1 (only when om not precomputed): R12 verbatim ----------
    if (!OM_PRE) {
        const int m_w = wv & 1, nt_w = (wv >> 1) & 1;
        f32x4 om_acc = {0.f, 0.f, 0.f, 0.f};

        auto stage1 = [&](int tap, int bufi) {
            const int ky = (tap * 11) >> 5, kx = tap - ky * 3;
            const int yy = h + ky - 1;
            const int xx = wbase + px + kx - 1;
            const bool v = ((unsigned)yy < 64u) & ((unsigned)xx < 64u);
            const int idx = v ? (yy << 6) + xx : 0;
            uint_t lo16[16];
            if (USE_PAIR) {
                const uint_t* p = xq + (idx << 8) + (slot << 4);
                uint4 r[4];
#pragma unroll
                for (int g = 0; g < 4; ++g) r[g] = *(const uint4*)(p + g * 4);
                const uint_t* rr = (const uint_t*)r;
#pragma unroll
                for (int c = 0; c < 16; ++c) lo16[c] = v ? (rr[c] & 0xffffu) : 0u;
            } else {
#pragma unroll
                for (int c = 0; c < 16; ++c) {
                    const int cin = (slot << 4) + c;
                    const float t0 = xb[(cin << 12) + idx];
                    lo16[c] = v ? (uint_t)f2bf(t0) : 0u;
                }
            }
            uint_t o[8];
#pragma unroll
            for (int k = 0; k < 8; ++k) o[k] = lo16[2 * k] | (lo16[2 * k + 1] << 16);
            uint_t* dst = (uint_t*)&As[bufi][0] + px * 132 + slot * 8;
            *(uint4*)dst       = make_uint4(o[0], o[1], o[2], o[3]);
            *(uint4*)(dst + 4) = make_uint4(o[4], o[5], o[6], o[7]);
        };
        auto mfma1 = [&](int tap) {
            if (wv < 4) {
                const short* cur = &As[tap & 1][0];
#pragma unroll
                for (int k2 = 0; k2 < 8; ++k2) {
                    const int ktg = tap * 8 + k2;
                    const short8 a = *(const short8*)&cur[((m_w << 4) + (lane & 15)) * 264 + k2 * 32 + quad * 8];
                    const short8 bf = *(const short8*)(woffb + ((ktg * 2 + nt_w) * 64 + lane) * 8);
                    om_acc = __builtin_amdgcn_mfma_f32_16x16x32_bf16(a, bf, om_acc, 0, 0, 0);
                }
            }
        };

        stage1(0, 0);
        __syncthreads();
        for (int tap = 0; tap < 9; ++tap) {
            if (tap < 8) stage1(tap + 1, (tap + 1) & 1);
            mfma1(tap);
            __syncthreads();
        }
        if (wv < 4) {
            const int c = (nt_w << 4) + (lane & 15);
            *(f32x4*)&om_s[c * 32 + (m_w << 4) + (quad << 2)] = om_acc;
        }
        __syncthreads();
    }

    // ---------- phase 2: per-(tap,px) 4-weight pair-gather params ----------
    if (tid < 288) {
        const int p2 = tid & 31, tap = tid >> 5;
        const int ky = (tap * 11) >> 5, kx = tap - ky * 3;
        const float* omp = OM_PRE ? (om_g + sid * 1024) : om_s;
        const float dyv = omp[(2 * tap) * 32 + p2] + b_off[2 * tap];
        const float dxv = omp[(2 * tap + 1) * 32 + p2] + b_off[2 * tap + 1];
        const float mo  = omp[(18 + tap) * 32 + p2] + b_off[18 + tap];
        const float mv  = 1.f / (1.f + expf(-mo));
        const float py  = dyv + (float)(h - 1 + ky);
        const float pxf = dxv + (float)(wbase + p2 - 1 + kx);
        const float y0f = floorf(py), x0f = floorf(pxf);
        const float wy = py - y0f,    wx = pxf - x0f;
        const float vy0 = (y0f >=  0.f && y0f <= 63.f) ? 1.f : 0.f;
        const float vy1 = (y0f >= -1.f && y0f <= 62.f) ? 1.f : 0.f;
        const int ry0 = (int)fminf(fmaxf(y0f, 0.f), 63.f);
        const int ry1 = (int)fminf(fmaxf(y0f + 1.f, 0.f), 63.f);
        const float rw0 = (1.f - wy) * vy0 * mv;
        const float rw1 = wy * vy1 * mv;
        const bool in01 = (x0f >= 0.f && x0f <= 62.f);
        const float wa = in01 ? (1.f - wx) : ((x0f == -1.f) ? wx : 0.f);
        const float wb = in01 ? wx : ((x0f == 63.f) ? (1.f - wx) : 0.f);
        const int bx = (int)fminf(fmaxf(x0f, 0.f), 62.f);
        pwt[tid]  = make_float4(wa * rw0, wb * rw0, wa * rw1, wb * rw1);
        pidx[tid] = make_int2(ry0 * 64 + bx, ry1 * 64 + bx);
    }
    __syncthreads();

    // ---------- phase 3: sampling + main GEMM (R12 structure) ----------
    f32x4 acc[2][2];
#pragma unroll
    for (int m = 0; m < 2; ++m)
#pragma unroll
        for (int nn = 0; nn < 2; ++nn) acc[m][nn] = f32x4{0.f, 0.f, 0.f, 0.f};

    const int nt_base = wv << 1;                      // wave's couts: wv*32..+31

    auto stage3 = [&](int tap, int bufi) {
        const float4 wt = pwt[tap * 32 + px];         // (w00,w01,w10,w11)
        const int2   ii = pidx[tap * 32 + px];
        uint_t o[8];
        if (USE_PAIR) {
            const uint_t* p0 = xq + (ii.x << 8) + (slot << 4);
            const uint_t* p1 = xq + (ii.y << 8) + (slot << 4);
            uint4 r0[4], r1[4];
#pragma unroll
            for (int g = 0; g < 4; ++g) {
                r0[g] = *(const uint4*)(p0 + g * 4);
                r1[g] = *(const uint4*)(p1 + g * 4);
            }
            const uint_t* a0 = (const uint_t*)r0;
            const uint_t* a1 = (const uint_t*)r1;
#pragma unroll
            for (int k = 0; k < 8; ++k) {
                float vv[2];
#pragma unroll
                for (int u = 0; u < 2; ++u) {
                    const int c = 2 * k + u;
                    vv[u] = bflo(a0[c]) * wt.x + bfhi(a0[c]) * wt.y
                          + bflo(a1[c]) * wt.z + bfhi(a1[c]) * wt.w;
                }
                o[k] = packbf2(vv[0], vv[1]);
            }
        } else {
#pragma unroll
            for (int k = 0; k < 8; ++k) {
                float vv[2];
#pragma unroll
                for (int u = 0; u < 2; ++u) {
                    const int cin = (slot << 4) + 2 * k + u;
                    const pairf pa = *(const pairf*)(xb + (cin << 12) + ii.x);
                    const pairf pb = *(const pairf*)(xb + (cin << 12) + ii.y);
                    vv[u] = pa.x * wt.x + pa.y * wt.y + pb.x * wt.z + pb.y * wt.w;
                }
                o[k] = packbf2(vv[0], vv[1]);
            }
        }
        uint_t* dst = (uint_t*)&As[bufi][0] + px * 132 + slot * 8;
        *(uint4*)dst       = make_uint4(o[0], o[1], o[2], o[3]);
        *(uint4*)(dst + 4) = make_uint4(o[4], o[5], o[6], o[7]);
    };
    auto mfma3 = [&](int tap) {
        const short* cur = &As[tap & 1][0];
#pragma unroll
        for (int k2 = 0; k2 < 8; ++k2) {
            const int ktg = tap * 8 + k2;
            short8 a0 = *(const short8*)&cur[(lane & 15) * 264 + k2 * 32 + quad * 8];
            short8 a1 = *(const short8*)&cur[((lane & 15) + 16) * 264 + k2 * 32 + quad * 8];
#pragma unroll
            for (int nn = 0; nn < 2; ++nn) {
                const short8 bf = *(const short8*)(wfrag + ((ktg * 16 + nt_base + nn) * 64 + lane) * 8);
                acc[0][nn] = __builtin_amdgcn_mfma_f32_16x16x32_bf16(a0, bf, acc[0][nn], 0, 0, 0);
                acc[1][nn] = __builtin_amdgcn_mfma_f32_16x16x32_bf16(a1, bf, acc[1][nn], 0, 0, 0);
            }
        }
    };

    stage3(0, 0);
    __syncthreads();
    for (int tap = 0; tap < 9; ++tap) {
        if (tap < 8) stage3(tap + 1, (tap + 1) & 1);
        mfma3(tap);
        __syncthreads();
    }

    // epilogue: w = wbase + m*16 + quad*4 + reg; cout n = wv*32 + nn*16 + (lane&15)
#pragma unroll
    for (int m = 0; m < 2; ++m) {
        const int w = wbase + (m << 4) + (quad << 2);
#pragma unroll
        for (int nn = 0; nn < 2; ++nn) {
            const int n = (wv << 5) + (nn << 4) + (lane & 15);
            float* op = out + (((size_t)((b << 8) + n)) << 12) + (h << 6) + w;
            *(f32x4*)op = acc[m][nn];
        }
    }
}

extern "C" void kernel_launch(void* const* d_in, const int* in_sizes, int n_in,
                              void* d_out, int out_size, void* d_ws, size_t ws_size,
                              hipStream_t stream) {
    const float* x      = (const float*)d_in[0];
    const float* w_off  = (const float*)d_in[1];
    const float* b_off  = (const float*)d_in[2];
    const float* w_conv = (const float*)d_in[3];
    float* out = (float*)d_out;

    const size_t xp_bytes = 16777216ull;             // xpairT
    const size_t wf_bytes = 1327104ull;              // wfrag
    const size_t om_bytes = 2097152ull;              // om_g (512 x 1024 fp32)
    const bool use_pair = (ws_size >= xp_bytes + wf_bytes);
    const bool use_om   = (ws_size >= xp_bytes + wf_bytes + om_bytes);

    uint_t*   xpair = (uint_t*)d_ws;
    ushort_t* wfrag = use_pair ? (ushort_t*)((char*)d_ws + xp_bytes)
                               : (ushort_t*)d_ws;
    float*    om_g  = (float*)((char*)d_ws + xp_bytes + wf_bytes);

    hipLaunchKernelGGL(k_pre_w, dim3(324), dim3(256), 0, stream,
                       w_conv, w_off, wfrag);

    const int XO = use_om ? 512 : 0;
    const int XT = use_pair ? 1024 : 0;
    if (XO + XT > 0)
        hipLaunchKernelGGL(k_pre_x, dim3(XO + XT), dim3(256), 0, stream,
                           x, wfrag, xpair, om_g, XO);

    if (use_om)
        hipLaunchKernelGGL((k_all<true, true>), dim3(512), dim3(512), 0, stream,
                           x, xpair, b_off, wfrag, om_g, out);
    else if (use_pair)
        hipLaunchKernelGGL((k_all<true, false>), dim3(512), dim3(512), 0, stream,
                           x, xpair, b_off, wfrag, om_g, out);
    else
        hipLaunchKernelGGL((k_all<false, false>), dim3(512), dim3(512), 0, stream,
                           x, xpair, b_off, wfrag, om_g, out);
}

// Round 17
// 169.102 us; speedup vs baseline: 1.5815x; 1.0505x over previous
//
#include <hip/hip_runtime.h>
#include <hip/hip_bf16.h>

// Modulated deformable conv, fp32 in/out. B=4, CIN=COUT=256, H=W=64, KS=3, PAD=1.
// R17: k_all untouched (62.5us measured R16). Prep re-pipelined:
//  D1 k_pre_a: xpairT transpose (1024 blk) + w_off swizzle (36 blk)
//  D2 k_pre_b: om GEMM staging from xpairT uint4s (512 blk) + w_conv swizzle (288)
//  D3 k_all  : phase2/3 only (om_g precomputed)
// ws: [xpairT 16MB][wfrag 1.33MB][om_g 2MB]; laddered fallback below.

#define WOFF_FRAG_OFF 589824
typedef unsigned short ushort_t;
typedef unsigned int   uint_t;

using short8 = __attribute__((ext_vector_type(8))) short;
using f32x4  = __attribute__((ext_vector_type(4))) float;

struct __attribute__((packed, aligned(4))) pairf { float x, y; };

__device__ inline ushort_t f2bf(float v) {
    unsigned u = __float_as_uint(v);
    unsigned r = u + 0x7fffu + ((u >> 16) & 1u);   // RNE (inputs finite)
    return (ushort_t)(r >> 16);
}
__device__ inline uint_t packbf2(float a, float b) {
    __hip_bfloat162 h = __float22bfloat162_rn(make_float2(a, b));
    return *(uint_t*)&h;                            // lo = a, hi = b
}
__device__ inline float bflo(uint_t u) { return __uint_as_float(u << 16); }
__device__ inline float bfhi(uint_t u) { return __uint_as_float(u & 0xffff0000u); }

// ---- k_pre_a: [0,1024) xpairT transpose; [1024,1060) w_off swizzle ----
__global__ __launch_bounds__(256) void k_pre_a(
    const float* __restrict__ x,
    const float* __restrict__ w_off,
    ushort_t* __restrict__ wfrag,
    uint_t* __restrict__ xpair)
{
    __shared__ uint_t tl[16 * 256];
    const int bid = blockIdx.x;
    const int tid = threadIdx.x;
    if (bid < 1024) {                                 // transpose (R13-verified)
        const int b    = bid >> 8;
        const int idx0 = (bid & 255) << 4;
        const float* xp = x + (b << 20) + (tid << 12) + idx0;
        float v[17];
#pragma unroll
        for (int g = 0; g < 4; ++g) {
            const float4 f = *(const float4*)(xp + g * 4);
            v[4 * g] = f.x; v[4 * g + 1] = f.y; v[4 * g + 2] = f.z; v[4 * g + 3] = f.w;
        }
        v[16] = ((idx0 & 63) != 48) ? xp[16] : 0.f;   // pair-hi never crosses row
#pragma unroll
        for (int i = 0; i < 16; ++i)
            tl[i * 256 + tid] = packbf2(v[i], v[i + 1]);
        __syncthreads();
        uint_t* op = xpair + (((b << 12) + idx0) << 8);
#pragma unroll
        for (int r = 0; r < 4; ++r) {
            const int l = r * 256 + tid;
            const int il = l >> 6, c = (l & 63) << 2;
            *(uint4*)(op + (il << 8) + c) = *(const uint4*)&tl[il * 256 + c];
        }
        return;
    }
    // w_off fragment rows (+pad), 36 blocks (HW-verified R13)
    const int i8 = (bid - 1024) * 256 + tid;          // 0..9215
    const int lane = i8 & 63;
    const int nt = (i8 >> 6) & 1;
    const int kt = i8 >> 7;                           // 0..71
    const int n = nt * 16 + (lane & 15);
    const int k0 = kt * 32 + ((lane >> 4) << 3);
    ushort_t v[8];
#pragma unroll
    for (int j = 0; j < 8; ++j) {
        const int kn = k0 + j;                        // tap-outer: kn = tap*256+cin
        const int cin = kn & 255, tap = kn >> 8;
        v[j] = (n < 27) ? f2bf(w_off[n * 2304 + cin * 9 + tap]) : (ushort_t)0;
    }
    uint4 o;
    o.x = (uint_t)v[0] | ((uint_t)v[1] << 16);
    o.y = (uint_t)v[2] | ((uint_t)v[3] << 16);
    o.z = (uint_t)v[4] | ((uint_t)v[5] << 16);
    o.w = (uint_t)v[6] | ((uint_t)v[7] << 16);
    *(uint4*)(wfrag + WOFF_FRAG_OFF + (size_t)i8 * 8) = o;
}

// ---- k_pre_b: [0,XO) om GEMM from xpairT; [XO,XO+288) w_conv swizzle ----
__global__ __launch_bounds__(256) void k_pre_b(
    const uint_t* __restrict__ xpair,
    const float* __restrict__ w_conv,
    const ushort_t* __restrict__ wfrag,
    float* __restrict__ om_g,
    int XO)
{
    __shared__ short As[2][32 * 264];                 // 33,792 B
    const int bid = blockIdx.x;
    const int tid = threadIdx.x;

    if (bid < XO) {
        // om GEMM: 32 px x 32 n, K=2304 tap-outer, staging from xpairT
        const int sid = ((bid & 7) << 6) | (bid >> 3);
        const int m0  = sid << 5;
        const int b   = m0 >> 12;
        const int h   = (m0 >> 6) & 63;
        const int wbase = m0 & 63;
        const int lane = tid & 63;
        const int wv   = tid >> 6;                    // 0..3
        const int quad = lane >> 4;
        const int px   = tid & 31;
        const int slot = tid >> 5;                    // 0..7: 32 cins each
        const uint_t* xq = xpair + (b << 20);
        const ushort_t* woffb = wfrag + WOFF_FRAG_OFF;
        const int m_w = wv & 1, nt_w = wv >> 1;

        f32x4 om_acc = {0.f, 0.f, 0.f, 0.f};

        auto stage = [&](int tap, int bufi) {
            const int ky = (tap * 11) >> 5, kx = tap - ky * 3;
            const int yy = h + ky - 1;
            const int xx = wbase + px + kx - 1;
            const bool v = ((unsigned)yy < 64u) & ((unsigned)xx < 64u);
            const int idx = v ? (yy << 6) + xx : 0;
            const uint_t* p = xq + (idx << 8) + (slot << 5);
            uint4 r[8];
#pragma unroll
            for (int g = 0; g < 8; ++g) r[g] = *(const uint4*)(p + g * 4);
            const uint_t* rr = (const uint_t*)r;
            uint_t o[16];
#pragma unroll
            for (int k = 0; k < 16; ++k) {
                const uint_t l0 = v ? (rr[2 * k] & 0xffffu) : 0u;
                const uint_t l1 = v ? (rr[2 * k + 1] & 0xffffu) : 0u;
                o[k] = l0 | (l1 << 16);
            }
            uint_t* dst = (uint_t*)&As[bufi][0] + px * 132 + (slot << 4);
#pragma unroll
            for (int g = 0; g < 4; ++g)
                *(uint4*)(dst + g * 4) = make_uint4(o[4*g], o[4*g+1], o[4*g+2], o[4*g+3]);
        };
        auto domfma = [&](int tap) {
            const short* cur = &As[tap & 1][0];
#pragma unroll
            for (int k2 = 0; k2 < 8; ++k2) {
                const int ktg = tap * 8 + k2;
                const short8 a = *(const short8*)&cur[((m_w << 4) + (lane & 15)) * 264 + k2 * 32 + quad * 8];
                const short8 bf = *(const short8*)(woffb + ((ktg * 2 + nt_w) * 64 + lane) * 8);
                om_acc = __builtin_amdgcn_mfma_f32_16x16x32_bf16(a, bf, om_acc, 0, 0, 0);
            }
        };

        stage(0, 0);
        __syncthreads();
        for (int tap = 0; tap < 9; ++tap) {
            if (tap < 8) stage(tap + 1, (tap + 1) & 1);
            domfma(tap);
            __syncthreads();
        }
        const int c = (nt_w << 4) + (lane & 15);
        *(f32x4*)(om_g + sid * 1024 + c * 32 + (m_w << 4) + (quad << 2)) = om_acc;
        return;
    }

    // w_conv fragment rows (HW-verified R13)
    const int i8 = (bid - XO) * 256 + tid;            // 0..73727
    const int lane = i8 & 63;
    const int nt = (i8 >> 6) & 15;
    const int kt = i8 >> 10;                          // 0..71
    const int n = nt * 16 + (lane & 15);
    const int k0 = kt * 32 + ((lane >> 4) << 3);
    ushort_t v[8];
#pragma unroll
    for (int j = 0; j < 8; ++j) {
        const int kn = k0 + j;
        const int cin = kn & 255, tap = kn >> 8;
        v[j] = f2bf(w_conv[n * 2304 + cin * 9 + tap]);
    }
    uint4 o;
    o.x = (uint_t)v[0] | ((uint_t)v[1] << 16);
    o.y = (uint_t)v[2] | ((uint_t)v[3] << 16);
    o.z = (uint_t)v[4] | ((uint_t)v[5] << 16);
    o.w = (uint_t)v[6] | ((uint_t)v[7] << 16);
    *(uint4*)(wfrag + (size_t)i8 * 8) = o;
}

// ---- fallback full swizzle (R16 k_pre_w, 324 blocks) ----
__global__ __launch_bounds__(256) void k_pre_w(
    const float* __restrict__ w_conv,
    const float* __restrict__ w_off,
    ushort_t* __restrict__ wfrag)
{
    const int wb = blockIdx.x;
    const int t  = threadIdx.x;
    if (wb < 288) {
        const int i8 = wb * 256 + t;
        const int lane = i8 & 63;
        const int nt = (i8 >> 6) & 15;
        const int kt = i8 >> 10;
        const int n = nt * 16 + (lane & 15);
        const int k0 = kt * 32 + ((lane >> 4) << 3);
        ushort_t v[8];
#pragma unroll
        for (int j = 0; j < 8; ++j) {
            const int kn = k0 + j;
            const int cin = kn & 255, tap = kn >> 8;
            v[j] = f2bf(w_conv[n * 2304 + cin * 9 + tap]);
        }
        uint4 o;
        o.x = (uint_t)v[0] | ((uint_t)v[1] << 16);
        o.y = (uint_t)v[2] | ((uint_t)v[3] << 16);
        o.z = (uint_t)v[4] | ((uint_t)v[5] << 16);
        o.w = (uint_t)v[6] | ((uint_t)v[7] << 16);
        *(uint4*)(wfrag + (size_t)i8 * 8) = o;
    } else {
        const int i8 = (wb - 288) * 256 + t;
        const int lane = i8 & 63;
        const int nt = (i8 >> 6) & 1;
        const int kt = i8 >> 7;
        const int n = nt * 16 + (lane & 15);
        const int k0 = kt * 32 + ((lane >> 4) << 3);
        ushort_t v[8];
#pragma unroll
        for (int j = 0; j < 8; ++j) {
            const int kn = k0 + j;
            const int cin = kn & 255, tap = kn >> 8;
            v[j] = (n < 27) ? f2bf(w_off[n * 2304 + cin * 9 + tap]) : (ushort_t)0;
        }
        uint4 o;
        o.x = (uint_t)v[0] | ((uint_t)v[1] << 16);
        o.y = (uint_t)v[2] | ((uint_t)v[3] << 16);
        o.z = (uint_t)v[4] | ((uint_t)v[5] << 16);
        o.w = (uint_t)v[6] | ((uint_t)v[7] << 16);
        *(uint4*)(wfrag + WOFF_FRAG_OFF + (size_t)i8 * 8) = o;
    }
}

// ---- k_all: R16 verbatim (62.5us measured) ----
template<bool USE_PAIR, bool OM_PRE>
__global__ __launch_bounds__(512, 4) void k_all(
    const float* __restrict__ x,
    const uint_t* __restrict__ xpair,
    const float* __restrict__ b_off,
    const ushort_t* __restrict__ wfrag,
    const float* __restrict__ om_g,
    float* __restrict__ out)
{
    __shared__ short As[2][32 * 264];
    __shared__ __align__(16) float4 pwt[9 * 32];
    __shared__ __align__(16) int2   pidx[9 * 32];
    float* om_s = (float*)&As[0][0];

    const int bid = blockIdx.x;
    const int sid = ((bid & 7) << 6) | (bid >> 3);
    const int m0  = sid << 5;
    const int b   = m0 >> 12;
    const int h   = (m0 >> 6) & 63;
    const int wbase = m0 & 63;
    const int tid  = threadIdx.x;
    const int lane = tid & 63;
    const int wv   = tid >> 6;
    const int quad = lane >> 4;
    const int px   = tid & 31;
    const int slot = tid >> 5;

    const float*  xb = x + (b << 20);
    const uint_t* xq = xpair + (b << 20);
    const ushort_t* woffb = wfrag + WOFF_FRAG_OFF;

    if (!OM_PRE) {
        const int m_w = wv & 1, nt_w = (wv >> 1) & 1;
        f32x4 om_acc = {0.f, 0.f, 0.f, 0.f};

        auto stage1 = [&](int tap, int bufi) {
            const int ky = (tap * 11) >> 5, kx = tap - ky * 3;
            const int yy = h + ky - 1;
            const int xx = wbase + px + kx - 1;
            const bool v = ((unsigned)yy < 64u) & ((unsigned)xx < 64u);
            const int idx = v ? (yy << 6) + xx : 0;
            uint_t lo16[16];
            if (USE_PAIR) {
                const uint_t* p = xq + (idx << 8) + (slot << 4);
                uint4 r[4];
#pragma unroll
                for (int g = 0; g < 4; ++g) r[g] = *(const uint4*)(p + g * 4);
                const uint_t* rr = (const uint_t*)r;
#pragma unroll
                for (int c = 0; c < 16; ++c) lo16[c] = v ? (rr[c] & 0xffffu) : 0u;
            } else {
#pragma unroll
                for (int c = 0; c < 16; ++c) {
                    const int cin = (slot << 4) + c;
                    const float t0 = xb[(cin << 12) + idx];
                    lo16[c] = v ? (uint_t)f2bf(t0) : 0u;
                }
            }
            uint_t o[8];
#pragma unroll
            for (int k = 0; k < 8; ++k) o[k] = lo16[2 * k] | (lo16[2 * k + 1] << 16);
            uint_t* dst = (uint_t*)&As[bufi][0] + px * 132 + slot * 8;
            *(uint4*)dst       = make_uint4(o[0], o[1], o[2], o[3]);
            *(uint4*)(dst + 4) = make_uint4(o[4], o[5], o[6], o[7]);
        };
        auto mfma1 = [&](int tap) {
            if (wv < 4) {
                const short* cur = &As[tap & 1][0];
#pragma unroll
                for (int k2 = 0; k2 < 8; ++k2) {
                    const int ktg = tap * 8 + k2;
                    const short8 a = *(const short8*)&cur[((m_w << 4) + (lane & 15)) * 264 + k2 * 32 + quad * 8];
                    const short8 bf = *(const short8*)(woffb + ((ktg * 2 + nt_w) * 64 + lane) * 8);
                    om_acc = __builtin_amdgcn_mfma_f32_16x16x32_bf16(a, bf, om_acc, 0, 0, 0);
                }
            }
        };

        stage1(0, 0);
        __syncthreads();
        for (int tap = 0; tap < 9; ++tap) {
            if (tap < 8) stage1(tap + 1, (tap + 1) & 1);
            mfma1(tap);
            __syncthreads();
        }
        if (wv < 4) {
            const int c = (nt_w << 4) + (lane & 15);
            *(f32x4*)&om_s[c * 32 + (m_w << 4) + (quad << 2)] = om_acc;
        }
        __syncthreads();
    }

    if (tid < 288) {
        const int p2 = tid & 31, tap = tid >> 5;
        const int ky = (tap * 11) >> 5, kx = tap - ky * 3;
        const float* omp = OM_PRE ? (om_g + sid * 1024) : om_s;
        const float dyv = omp[(2 * tap) * 32 + p2] + b_off[2 * tap];
        const float dxv = omp[(2 * tap + 1) * 32 + p2] + b_off[2 * tap + 1];
        const float mo  = omp[(18 + tap) * 32 + p2] + b_off[18 + tap];
        const float mv  = 1.f / (1.f + expf(-mo));
        const float py  = dyv + (float)(h - 1 + ky);
        const float pxf = dxv + (float)(wbase + p2 - 1 + kx);
        const float y0f = floorf(py), x0f = floorf(pxf);
        const float wy = py - y0f,    wx = pxf - x0f;
        const float vy0 = (y0f >=  0.f && y0f <= 63.f) ? 1.f : 0.f;
        const float vy1 = (y0f >= -1.f && y0f <= 62.f) ? 1.f : 0.f;
        const int ry0 = (int)fminf(fmaxf(y0f, 0.f), 63.f);
        const int ry1 = (int)fminf(fmaxf(y0f + 1.f, 0.f), 63.f);
        const float rw0 = (1.f - wy) * vy0 * mv;
        const float rw1 = wy * vy1 * mv;
        const bool in01 = (x0f >= 0.f && x0f <= 62.f);
        const float wa = in01 ? (1.f - wx) : ((x0f == -1.f) ? wx : 0.f);
        const float wb = in01 ? wx : ((x0f == 63.f) ? (1.f - wx) : 0.f);
        const int bx = (int)fminf(fmaxf(x0f, 0.f), 62.f);
        pwt[tid]  = make_float4(wa * rw0, wb * rw0, wa * rw1, wb * rw1);
        pidx[tid] = make_int2(ry0 * 64 + bx, ry1 * 64 + bx);
    }
    __syncthreads();

    f32x4 acc[2][2];
#pragma unroll
    for (int m = 0; m < 2; ++m)
#pragma unroll
        for (int nn = 0; nn < 2; ++nn) acc[m][nn] = f32x4{0.f, 0.f, 0.f, 0.f};

    const int nt_base = wv << 1;

    auto stage3 = [&](int tap, int bufi) {
        const float4 wt = pwt[tap * 32 + px];
        const int2   ii = pidx[tap * 32 + px];
        uint_t o[8];
        if (USE_PAIR) {
            const uint_t* p0 = xq + (ii.x << 8) + (slot << 4);
            const uint_t* p1 = xq + (ii.y << 8) + (slot << 4);
            uint4 r0[4], r1[4];
#pragma unroll
            for (int g = 0; g < 4; ++g) {
                r0[g] = *(const uint4*)(p0 + g * 4);
                r1[g] = *(const uint4*)(p1 + g * 4);
            }
            const uint_t* a0 = (const uint_t*)r0;
            const uint_t* a1 = (const uint_t*)r1;
#pragma unroll
            for (int k = 0; k < 8; ++k) {
                float vv[2];
#pragma unroll
                for (int u = 0; u < 2; ++u) {
                    const int c = 2 * k + u;
                    vv[u] = bflo(a0[c]) * wt.x + bfhi(a0[c]) * wt.y
                          + bflo(a1[c]) * wt.z + bfhi(a1[c]) * wt.w;
                }
                o[k] = packbf2(vv[0], vv[1]);
            }
        } else {
#pragma unroll
            for (int k = 0; k < 8; ++k) {
                float vv[2];
#pragma unroll
                for (int u = 0; u < 2; ++u) {
                    const int cin = (slot << 4) + 2 * k + u;
                    const pairf pa = *(const pairf*)(xb + (cin << 12) + ii.x);
                    const pairf pb = *(const pairf*)(xb + (cin << 12) + ii.y);
                    vv[u] = pa.x * wt.x + pa.y * wt.y + pb.x * wt.z + pb.y * wt.w;
                }
                o[k] = packbf2(vv[0], vv[1]);
            }
        }
        uint_t* dst = (uint_t*)&As[bufi][0] + px * 132 + slot * 8;
        *(uint4*)dst       = make_uint4(o[0], o[1], o[2], o[3]);
        *(uint4*)(dst + 4) = make_uint4(o[4], o[5], o[6], o[7]);
    };
    auto mfma3 = [&](int tap) {
        const short* cur = &As[tap & 1][0];
#pragma unroll
        for (int k2 = 0; k2 < 8; ++k2) {
            const int ktg = tap * 8 + k2;
            short8 a0 = *(const short8*)&cur[(lane & 15) * 264 + k2 * 32 + quad * 8];
            short8 a1 = *(const short8*)&cur[((lane & 15) + 16) * 264 + k2 * 32 + quad * 8];
#pragma unroll
            for (int nn = 0; nn < 2; ++nn) {
                const short8 bf = *(const short8*)(wfrag + ((ktg * 16 + nt_base + nn) * 64 + lane) * 8);
                acc[0][nn] = __builtin_amdgcn_mfma_f32_16x16x32_bf16(a0, bf, acc[0][nn], 0, 0, 0);
                acc[1][nn] = __builtin_amdgcn_mfma_f32_16x16x32_bf16(a1, bf, acc[1][nn], 0, 0, 0);
            }
        }
    };

    stage3(0, 0);
    __syncthreads();
    for (int tap = 0; tap < 9; ++tap) {
        if (tap < 8) stage3(tap + 1, (tap + 1) & 1);
        mfma3(tap);
        __syncthreads();
    }

#pragma unroll
    for (int m = 0; m < 2; ++m) {
        const int w = wbase + (m << 4) + (quad << 2);
#pragma unroll
        for (int nn = 0; nn < 2; ++nn) {
            const int n = (wv << 5) + (nn << 4) + (lane & 15);
            float* op = out + (((size_t)((b << 8) + n)) << 12) + (h << 6) + w;
            *(f32x4*)op = acc[m][nn];
        }
    }
}

extern "C" void kernel_launch(void* const* d_in, const int* in_sizes, int n_in,
                              void* d_out, int out_size, void* d_ws, size_t ws_size,
                              hipStream_t stream) {
    const float* x      = (const float*)d_in[0];
    const float* w_off  = (const float*)d_in[1];
    const float* b_off  = (const float*)d_in[2];
    const float* w_conv = (const float*)d_in[3];
    float* out = (float*)d_out;

    const size_t xp_bytes = 16777216ull;             // xpairT
    const size_t wf_bytes = 1327104ull;              // wfrag
    const size_t om_bytes = 2097152ull;              // om_g (512 x 1024 fp32)
    const bool use_pair = (ws_size >= xp_bytes + wf_bytes);
    const bool use_om   = (ws_size >= xp_bytes + wf_bytes + om_bytes);

    uint_t*   xpair = (uint_t*)d_ws;
    ushort_t* wfrag = use_pair ? (ushort_t*)((char*)d_ws + xp_bytes)
                               : (ushort_t*)d_ws;
    float*    om_g  = (float*)((char*)d_ws + xp_bytes + wf_bytes);

    if (use_pair) {
        hipLaunchKernelGGL(k_pre_a, dim3(1060), dim3(256), 0, stream,
                           x, w_off, wfrag, xpair);
        const int XO = use_om ? 512 : 0;
        hipLaunchKernelGGL(k_pre_b, dim3(XO + 288), dim3(256), 0, stream,
                           xpair, w_conv, wfrag, om_g, XO);
        if (use_om)
            hipLaunchKernelGGL((k_all<true, true>), dim3(512), dim3(512), 0, stream,
                               x, xpair, b_off, wfrag, om_g, out);
        else
            hipLaunchKernelGGL((k_all<true, false>), dim3(512), dim3(512), 0, stream,
                               x, xpair, b_off, wfrag, om_g, out);
    } else {
        hipLaunchKernelGGL(k_pre_w, dim3(324), dim3(256), 0, stream,
                           w_conv, w_off, wfrag);
        hipLaunchKernelGGL((k_all<false, false>), dim3(512), dim3(512), 0, stream,
                           x, xpair, b_off, wfrag, om_g, out);
    }
}